// Round 8
// baseline (173.874 us; speedup 1.0000x reference)
//
#include <hip/hip_runtime.h>
#include <math.h>

// CTC loss forward: T=1024, N=128, C=256, S=64, L=2S+1=129, blank=0.
constexpr int kT = 1024;
constexpr int kN = 128;
constexpr int kC = 256;
constexpr float NEGV = -1e30f;
constexpr int kRow = 260;             // floats per t4-group: 65 states x 4 t's
constexpr int CHUNK = 64;             // t-steps per staged chunk
constexpr int NCHUNK = kT / CHUNK;    // 16
constexpr int CHUNKF = 16 * kRow;     // 4160 floats per chunk
constexpr int CHUNKB = CHUNKF * 4;    // 16640 B (multiple of 16)
constexpr float LOG2E = 1.4426950408889634f;
constexpr float LN2 = 0.6931471805599453f;

#if __has_builtin(__builtin_amdgcn_exp2f)
#define EXP2(x) __builtin_amdgcn_exp2f(x)
#else
#define EXP2(x) exp2f(x)
#endif
#if __has_builtin(__builtin_amdgcn_logf)
#define LOG2(x) __builtin_amdgcn_logf(x)
#else
#define LOG2(x) log2f(x)
#endif

struct TrueT { static constexpr bool value = true; };
struct FalseT { static constexpr bool value = false; };

__device__ __forceinline__ float lse2_2(float a, float b) {  // log2(2^a + 2^b)
    const float m = fmaxf(a, b);
    const float d = fminf(a, b) - m;
    return m + LOG2(1.0f + EXP2(d));
}

__device__ __forceinline__ float lse2_e(float a, float b) {  // ln(e^a + e^b)
    const float m = fmaxf(a, b);
    return m + __logf(1.0f + __expf(fminf(a, b) - m));
}

__device__ __forceinline__ float lse3_e(float a, float b, float c) {
    const float m = fmaxf(fmaxf(a, b), c);
    return m + __logf(__expf(a - m) + __expf(b - m) + __expf(c - m));
}

// Kernel 1: per-row logsumexp over C=256. GATHER mode: block = (n, t4) covers
// 4 consecutive t for one n; writes BASE-2 log-probs in blocked-transposed
// layout lpg[n][t4][s][j] (s=0 blank, s=1+k label k; j=t&3), coalesced via LDS.
template <bool GATHER>
__global__ __launch_bounds__(256) void k_lse(const float* __restrict__ logits,
                                             const int* __restrict__ y,
                                             float* __restrict__ lpg,
                                             float* __restrict__ lse_out) {
    __shared__ float srow[4][kC];
    __shared__ float sT[4][65];
    const int w = threadIdx.x >> 6;
    const int lane = threadIdx.x & 63;
    const int n = blockIdx.x & (kN - 1);
    const int t4 = blockIdx.x >> 7;
    const int t = t4 * 4 + w;
    const int row = t * kN + n;

    const float4 v = reinterpret_cast<const float4*>(logits + (size_t)row * kC)[lane];
    float m = fmaxf(fmaxf(v.x, v.y), fmaxf(v.z, v.w));
#pragma unroll
    for (int o = 32; o > 0; o >>= 1) m = fmaxf(m, __shfl_xor(m, o));
    float s = __expf(v.x - m) + __expf(v.y - m) + __expf(v.z - m) + __expf(v.w - m);
#pragma unroll
    for (int o = 32; o > 0; o >>= 1) s += __shfl_xor(s, o);

    if (GATHER) {
        const float log2s = LOG2(s);
        float* sr = srow[w];
        reinterpret_cast<float4*>(sr)[lane] = v;
        const int cls = y[(n << 6) + lane];  // labels in [1, C)
        sT[w][1 + lane] = (sr[cls] - m) * LOG2E - log2s;
        if (lane == 0) sT[w][0] = (v.x - m) * LOG2E - log2s;  // blank
        __syncthreads();
        float* op = lpg + (size_t)n * (kT / 4) * kRow + (size_t)t4 * kRow;
        const int tid = threadIdx.x;
        op[tid] = sT[tid & 3][tid >> 2];            // idx = s*4 + j
        if (tid < 4) op[256 + tid] = sT[tid][64];   // s = 64, j = tid
    } else {
        if (lane == 0) lse_out[row] = m + __logf(s);
    }
}

// One DP step, log2 domain. Lane l owns states (2l, 2l+1); lane 63 also owns
// state 128 (aC, fed by its own aB = state 127). Halo (hA,hB) = states
// (2l-16, 2l-15), a redundant copy of lane l-8's pair, so the row-head
// boundary value (state 32r-1) is available WITHIN the row as hB[j=7],
// delivered by DPP row_ror:9 into the `old` operand of row_shr:1.
template <bool FRZ>
__device__ __forceinline__ void dp_step(float& aA, float& aB, float& aC,
                                        float& hA, float& hB, float lpb,
                                        float lpy, float hlpy, bool skip,
                                        bool hskip, bool commit) {
    const int aBi = __float_as_int(aB);
    const int hBi = __float_as_int(hB);
    const int r9 = __builtin_amdgcn_update_dpp(0, hBi, 0x129 /*row_ror:9*/, 0xF, 0xF, true);
    const float am1 = __int_as_float(__builtin_amdgcn_update_dpp(
        r9, aBi, 0x111 /*row_shr:1*/, 0xF, 0xF, false));  // heads take hB[7] of own row
    const float ham1 = __int_as_float(__builtin_amdgcn_update_dpp(
        0, hBi, 0x111, 0xF, 0xF, true));  // halo heads: 0 (garbage, validity-safe)
    const float am1s = skip ? am1 : NEGV;
    const float hm1s = hskip ? ham1 : NEGV;

    // nB = lpy + lse3(aB, aA, am1s): max3/med3 2-exp form
    const float mB = fmaxf(fmaxf(aB, aA), am1s);
    const float dB1 = fmaxf(fminf(aB, aA), fminf(fmaxf(aB, aA), am1s)) - mB;  // med - max
    const float dB2 = fminf(fminf(aB, aA), am1s) - mB;                        // min - max
    const float nB = (lpy + mB) + LOG2(1.0f + EXP2(dB1) + EXP2(dB2));
    // nA = lpb + lse2(aA, am1)   (lane 0: am1 == NEGV via forced row-0 halo)
    const float mA = fmaxf(aA, am1);
    const float nA = (lpb + mA) + LOG2(1.0f + EXP2(fminf(aA, am1) - mA));
    // nC = lpb + lse2(aC, aB)    (state 128; meaningful at lane 63 only)
    const float mC = fmaxf(aC, aB);
    const float nC = (lpb + mC) + LOG2(1.0f + EXP2(fminf(aC, aB) - mC));
    // halo updates (same recurrences, shifted by -16 states)
    const float mhB = fmaxf(fmaxf(hB, hA), hm1s);
    const float dh1 = fmaxf(fminf(hB, hA), fminf(fmaxf(hB, hA), hm1s)) - mhB;
    const float dh2 = fminf(fminf(hB, hA), hm1s) - mhB;
    const float nhB = (hlpy + mhB) + LOG2(1.0f + EXP2(dh1) + EXP2(dh2));
    const float mhA = fmaxf(hA, ham1);
    const float nhA = (lpb + mhA) + LOG2(1.0f + EXP2(fminf(hA, ham1) - mhA));

    if (FRZ) {
        aA = commit ? nA : aA;
        aB = commit ? nB : aB;
        aC = commit ? nC : aC;
        hA = commit ? nhA : hA;
        hB = commit ? nhB : hB;
    } else {
        aA = nA; aB = nB; aC = nC; hA = nhA; hB = nhB;
    }
}

// Kernel 2 (fast): log2-domain alpha recursion, halo edition. One block per n.
// Wave 0 runs the DP; waves 1-3 double-buffer 64-t chunks of lpg into LDS.
__global__ __launch_bounds__(256) void k_dp_fast(const float* __restrict__ lpg,
                                                 const int* __restrict__ y,
                                                 const int* __restrict__ xlens,
                                                 const int* __restrict__ ylens,
                                                 float* __restrict__ nll_out) {
    __shared__ float sbuf[2][CHUNKF];
    const int n = blockIdx.x;
    const int wid = threadIdx.x >> 6;
    const int l = threadIdx.x & 63;
    const char* src = (const char*)(lpg + (size_t)n * (kT / 4) * kRow);

    auto stage = [&](int c, int b) {
        const int wbase = (wid - 1) * 64;  // wave-uniform
        const char* gs = src + (size_t)c * CHUNKB;
        char* ls = (char*)&sbuf[b][0];
#pragma unroll
        for (int r = 0; r < (CHUNKB / 16 + 191) / 192; ++r) {
            const int wi = wbase + r * 192;  // wave-uniform word index
            if (wi + l < CHUNKB / 16) {
                __builtin_amdgcn_global_load_lds(
                    (const __attribute__((address_space(1))) void*)(gs + (size_t)(wi + l) * 16),
                    (__attribute__((address_space(3))) void*)(ls + (size_t)wi * 16), 16, 0, 0);
            }
        }
    };

    if (wid > 0) stage(0, 0);
    __syncthreads();

    const int yl = ylens[n];
    const int xl = xlens[n];
    const int ycur = y[(n << 6) + l];
    const int yprev = __shfl_up(ycur, 1);
    const bool skip = (l >= 1) && (ycur != yprev);   // skip into state 2l+1
    const int hski = __shfl_up((int)skip, 8);
    const bool hskip = (l >= 8) && (hski != 0);      // skip for halo odd state
    const int hs = (l < 8) ? 1 : (l - 7);            // halo label slot in LDS row

    float aA = NEGV, aB = NEGV, aC = NEGV, hA = NEGV, hB = NEGV;
    if (wid == 0) {
        aA = (l == 0) ? sbuf[0][0] : NEGV;  // lp[t=0][s=0]
        aB = (l == 0) ? sbuf[0][4] : NEGV;  // lp[t=0][s=1]
    }

    auto refresh = [&]() {  // halo <- owned pair of lane l-8; row-0 halo -> NEGV
        const float tA = __shfl_up(aA, 8);
        const float tB = __shfl_up(aB, 8);
        hA = (l < 8) ? NEGV : tA;
        hB = (l < 8) ? NEGV : tB;
    };

#define PIN4(v4) asm volatile("" : "+v"(v4.x), "+v"(v4.y), "+v"(v4.z), "+v"(v4.w))
#define LOADG(G, D)                                                         \
    do {                                                                    \
        _Pragma("unroll") for (int q_ = 0; q_ < 4; ++q_) {                  \
            const int rb_ = ((G) * 4 + q_) * kRow;                          \
            float4 t0_ = *(const float4*)&B[rb_];                           \
            float4 t1_ = *(const float4*)&B[rb_ + 4 + 4 * l];               \
            float4 t2_ = *(const float4*)&B[rb_ + 4 * hs];                  \
            PIN4(t0_); PIN4(t1_); PIN4(t2_);                                \
            pb[D][q_][0] = t0_.x; pb[D][q_][1] = t0_.y;                     \
            pb[D][q_][2] = t0_.z; pb[D][q_][3] = t0_.w;                     \
            py[D][q_][0] = t1_.x; py[D][q_][1] = t1_.y;                     \
            py[D][q_][2] = t1_.z; py[D][q_][3] = t1_.w;                     \
            ph[D][q_][0] = t2_.x; ph[D][q_][1] = t2_.y;                     \
            ph[D][q_][2] = t2_.z; ph[D][q_][3] = t2_.w;                     \
        }                                                                   \
    } while (0)
#define DP_STEP(G, Q, JJ, CUR)                                              \
    do {                                                                    \
        const int t_ = tb0 + (G) * 16 + (Q) * 4 + (JJ);                     \
        const bool commit_ = ((t_ > 0) & (t_ < xl));                        \
        dp_step<decltype(FRZC)::value>(aA, aB, aC, hA, hB, pb[CUR][Q][JJ],  \
                                       py[CUR][Q][JJ], ph[CUR][Q][JJ],      \
                                       skip, hskip, commit_);               \
    } while (0)

    for (int c = 0; c < NCHUNK; ++c) {
        if (wid > 0) {
            if (c + 1 < NCHUNK) stage(c + 1, (c + 1) & 1);
        } else {
            const float* B = sbuf[c & 1];
            const int tb0 = c * CHUNK;
            auto chunk_body = [&](auto FRZC) {
                float pb[2][4][4], py[2][4][4], ph[2][4][4];
                LOADG(0, 0);
#pragma unroll
                for (int g = 0; g < 4; ++g) {
                    const int cur = g & 1, nxt = cur ^ 1;
                    DP_STEP(g, 0, 0, cur);
                    refresh();  // before t = 16g+1 (t mod 8 == 1)
                    DP_STEP(g, 0, 1, cur);
                    if (g < 3) LOADG(g + 1, nxt);  // issued here; drained by j==9 refresh
                    DP_STEP(g, 0, 2, cur);
                    DP_STEP(g, 0, 3, cur);
#pragma unroll
                    for (int jj = 0; jj < 4; ++jj) DP_STEP(g, 1, jj, cur);
                    DP_STEP(g, 2, 0, cur);
                    refresh();  // before t = 16g+9
                    DP_STEP(g, 2, 1, cur);
                    DP_STEP(g, 2, 2, cur);
                    DP_STEP(g, 2, 3, cur);
#pragma unroll
                    for (int jj = 0; jj < 4; ++jj) DP_STEP(g, 3, jj, cur);
                }
            };
            if (c == 0 || xl < kT) chunk_body(TrueT{});   // needs t>0 / t<xl guards
            else chunk_body(FalseT{});                    // no per-step cndmasks
        }
        __syncthreads();
    }

    if (wid == 0) {
        // alpha[2*yl] and alpha[2*yl-1]; yl in [16,64]
        const float la = (yl < 64) ? __shfl(aA, yl) : __shfl(aC, 63);
        const float lb = __shfl(aB, yl - 1);
        if (l == 0) {
            float nll = -lse2_2(la, lb) * LN2;  // back to nats
            if (!(isfinite(nll) && nll < 1e29f)) nll = 0.0f;  // zero_infinity
            nll_out[n] = nll / (float)yl;
        }
    }
#undef DP_STEP
#undef LOADG
#undef PIN4
}

// Fallback DP (no gather workspace): log-domain, gathers raw logits. Slow but correct.
template <int PFB>
__global__ __launch_bounds__(64) void k_dp_fb(const float* __restrict__ logits,
                                              const float* __restrict__ lsearr,
                                              const int* __restrict__ y,
                                              const int* __restrict__ xlens,
                                              const int* __restrict__ ylens,
                                              float* __restrict__ nll_out) {
    const int n = blockIdx.x;
    const int l = threadIdx.x;
    const int yl = ylens[n];
    const int xl = xlens[n];
    const int ycur = y[(n << 6) + l];
    const int yprev = __shfl_up(ycur, 1);
    const bool skip = (l >= 1) && (ycur != yprev);

    auto load_lp = [&](int t, float& lpb, float& lpy) {
        const float* p = logits + ((size_t)t * kN + n) * kC;
        const float d = lsearr[t * kN + n];
        lpb = p[0] - d;
        lpy = p[ycur] - d;
    };

    float lpb0, lpy0;
    load_lp(0, lpb0, lpy0);
    float aA = (l == 0) ? lpb0 : NEGV;
    float aB = (l == 0) ? lpy0 : NEGV;
    float aC = NEGV;

    float pb[PFB], py[PFB];
#pragma unroll
    for (int k = 0; k < PFB; ++k) load_lp(1 + k, pb[k], py[k]);

    for (int tb = 1; tb < kT; tb += PFB) {
#pragma unroll
        for (int k = 0; k < PFB; ++k) {
            const int t = tb + k;
            if (t < kT) {
                const float lpb = pb[k], lpy = py[k];
                if (t + PFB < kT) load_lp(t + PFB, pb[k], py[k]);
                float am1 = __shfl_up(aB, 1);
                if (l == 0) am1 = NEGV;
                const float nA = lpb + lse2_e(aA, am1);
                const float nB = lpy + lse3_e(aB, aA, skip ? am1 : NEGV);
                float nC = aC;
                if (l == 63) nC = lpb + lse2_e(aC, aB);
                if (t < xl) { aA = nA; aB = nB; aC = nC; }
            }
        }
    }

    __shared__ float st[130];
    st[2 * l] = aA;
    st[2 * l + 1] = aB;
    if (l == 63) st[128] = aC;
    __syncthreads();
    if (l == 0) {
        const int end = 2 * yl;
        float nll = -lse2_e(st[end], st[end - 1]);
        if (!(isfinite(nll) && nll < 1e29f)) nll = 0.0f;
        nll_out[n] = nll / (float)yl;
    }
}

__global__ __launch_bounds__(128) void k_reduce(const float* __restrict__ nll,
                                                float* __restrict__ out) {
    const int tid = threadIdx.x;
    float v = nll[tid];
#pragma unroll
    for (int o = 32; o > 0; o >>= 1) v += __shfl_xor(v, o);
    __shared__ float partial[2];
    if ((tid & 63) == 0) partial[tid >> 6] = v;
    __syncthreads();
    if (tid == 0) out[0] = (partial[0] + partial[1]) * (1.0f / (float)kN);
}

extern "C" void kernel_launch(void* const* d_in, const int* in_sizes, int n_in,
                              void* d_out, int out_size, void* d_ws, size_t ws_size,
                              hipStream_t stream) {
    const float* logits = (const float*)d_in[0];
    const int* y = (const int*)d_in[1];
    const int* xlens = (const int*)d_in[2];
    const int* ylens = (const int*)d_in[3];
    float* out = (float*)d_out;

    const size_t need_full =
        (size_t)kN * (kT / 4) * kRow * sizeof(float) + kN * sizeof(float);
    const int rows = kT * kN;

    if (ws_size >= need_full) {
        float* lpg = (float*)d_ws;
        float* nll = lpg + (size_t)kN * (kT / 4) * kRow;
        k_lse<true><<<rows / 4, 256, 0, stream>>>(logits, y, lpg, nullptr);
        k_dp_fast<<<kN, 256, 0, stream>>>(lpg, y, xlens, ylens, nll);
        k_reduce<<<1, kN, 0, stream>>>(nll, out);
    } else {
        float* lsearr = (float*)d_ws;
        float* nll = lsearr + (size_t)rows;
        k_lse<false><<<rows / 4, 256, 0, stream>>>(logits, y, nullptr, lsearr);
        k_dp_fb<8><<<kN, 64, 0, stream>>>(logits, lsearr, y, xlens, ylens, nll);
        k_reduce<<<1, kN, 0, stream>>>(nll, out);
    }
}

// Round 10
// 152.782 us; speedup vs baseline: 1.1381x; 1.1381x over previous
//
#include <hip/hip_runtime.h>
#include <math.h>

// CTC loss forward: T=1024, N=128, C=256, S=64, L=2S+1=129, blank=0.
constexpr int kT = 1024;
constexpr int kN = 128;
constexpr int kC = 256;
constexpr float NEGV = -1e30f;
constexpr int kRow = 260;             // floats per t4-group: 65 states x 4 t's
constexpr int kRowB = kRow * 4;       // 1040 bytes
constexpr int CHUNK = 64;             // t-steps per staged chunk
constexpr int NCHUNK = kT / CHUNK;    // 16
constexpr int CHUNKF = 16 * kRow;     // 4160 floats per chunk
constexpr int CHUNKB = CHUNKF * 4;    // 16640 B (multiple of 16)
constexpr float LOG2E = 1.4426950408889634f;
constexpr float LN2 = 0.6931471805599453f;

using f32x4 = __attribute__((ext_vector_type(4))) float;

#if __has_builtin(__builtin_amdgcn_exp2f)
#define EXP2(x) __builtin_amdgcn_exp2f(x)
#else
#define EXP2(x) exp2f(x)
#endif
#if __has_builtin(__builtin_amdgcn_logf)
#define LOG2(x) __builtin_amdgcn_logf(x)
#else
#define LOG2(x) log2f(x)
#endif

struct TrueT { static constexpr bool value = true; };
struct FalseT { static constexpr bool value = false; };

__device__ __forceinline__ float lse2_2(float a, float b) {  // log2(2^a + 2^b)
    const float m = fmaxf(a, b);
    const float d = fminf(a, b) - m;
    return m + LOG2(1.0f + EXP2(d));
}

__device__ __forceinline__ float lse2_e(float a, float b) {  // ln(e^a + e^b)
    const float m = fmaxf(a, b);
    return m + __logf(1.0f + __expf(fminf(a, b) - m));
}

__device__ __forceinline__ float lse3_e(float a, float b, float c) {
    const float m = fmaxf(fmaxf(a, b), c);
    return m + __logf(__expf(a - m) + __expf(b - m) + __expf(c - m));
}

// Kernel 1: per-row logsumexp over C=256. GATHER mode: block = (n, t4) covers
// 4 consecutive t for one n; writes BASE-2 log-probs in blocked-transposed
// layout lpg[n][t4][s][j] (s=0 blank, s=1+k label k; j=t&3), coalesced via LDS.
template <bool GATHER>
__global__ __launch_bounds__(256) void k_lse(const float* __restrict__ logits,
                                             const int* __restrict__ y,
                                             float* __restrict__ lpg,
                                             float* __restrict__ lse_out) {
    __shared__ float srow[4][kC];
    __shared__ float sT[4][65];
    const int w = threadIdx.x >> 6;
    const int lane = threadIdx.x & 63;
    const int n = blockIdx.x & (kN - 1);
    const int t4 = blockIdx.x >> 7;
    const int t = t4 * 4 + w;
    const int row = t * kN + n;

    const float4 v = reinterpret_cast<const float4*>(logits + (size_t)row * kC)[lane];
    float m = fmaxf(fmaxf(v.x, v.y), fmaxf(v.z, v.w));
#pragma unroll
    for (int o = 32; o > 0; o >>= 1) m = fmaxf(m, __shfl_xor(m, o));
    float s = __expf(v.x - m) + __expf(v.y - m) + __expf(v.z - m) + __expf(v.w - m);
#pragma unroll
    for (int o = 32; o > 0; o >>= 1) s += __shfl_xor(s, o);

    if (GATHER) {
        const float log2s = LOG2(s);
        float* sr = srow[w];
        reinterpret_cast<float4*>(sr)[lane] = v;
        const int cls = y[(n << 6) + lane];  // labels in [1, C)
        sT[w][1 + lane] = (sr[cls] - m) * LOG2E - log2s;
        if (lane == 0) sT[w][0] = (v.x - m) * LOG2E - log2s;  // blank
        __syncthreads();
        float* op = lpg + (size_t)n * (kT / 4) * kRow + (size_t)t4 * kRow;
        const int tid = threadIdx.x;
        op[tid] = sT[tid & 3][tid >> 2];            // idx = s*4 + j
        if (tid < 4) op[256 + tid] = sT[tid][64];   // s = 64, j = tid
    } else {
        if (lane == 0) lse_out[row] = m + __logf(s);
    }
}

// One DP step, log2 domain (validated r7 structure + r8's 2-exp lse3).
// Lane l owns states (2l, 2l+1); lane 0 also owns state 128 (aC, fed by
// am1 = aB[63] via the readlane/row_shr wrap).
template <bool FRZ>
__device__ __forceinline__ void dp_step(float& aA, float& aB, float& aC,
                                        float lpb, float lpy, bool skip,
                                        int lgrp, int l, bool commit) {
    const int bi = __float_as_int(aB);
    const int b15 = __builtin_amdgcn_readlane(bi, 15);
    const int b31 = __builtin_amdgcn_readlane(bi, 31);
    const int b47 = __builtin_amdgcn_readlane(bi, 47);
    const int b63 = __builtin_amdgcn_readlane(bi, 63);
    const int bndi = (lgrp == 0) ? b63 : (lgrp == 1) ? b15 : (lgrp == 2) ? b31 : b47;
    const float am1 = __int_as_float(__builtin_amdgcn_update_dpp(
        bndi, bi, 0x111 /*row_shr:1*/, 0xF, 0xF, false));
    const float am1s = skip ? am1 : NEGV;
    // nB = lpy + lse3(aB, aA, am1s): med3 2-exp form
    const float x = fmaxf(aB, aA), yv = fminf(aB, aA);
    const float mB = fmaxf(x, am1s);
    const float dB1 = fmaxf(yv, fminf(x, am1s)) - mB;  // med - max
    const float dB2 = fminf(yv, am1s) - mB;            // min - max
    const float nB = (lpy + mB) + LOG2(1.0f + (EXP2(dB1) + EXP2(dB2)));
    // states 2l / 128 share one lse2 (lane 0's slot computes state 128)
    const float u = (l == 0) ? aC : aA;
    const float mA = fmaxf(u, am1);
    const float lseA = mA + LOG2(1.0f + EXP2(fminf(u, am1) - mA));
    const float nA = lpb + ((l == 0) ? aA : lseA);
    const float nC = lpb + lseA;  // meaningful at lane 0 only
    if (FRZ) {
        aA = commit ? nA : aA;
        aB = commit ? nB : aB;
        aC = commit ? nC : aC;
    } else {
        aA = nA; aB = nB; aC = nC;
    }
}

__device__ __forceinline__ unsigned lds_off(const void* p) {
    return (unsigned)(unsigned long long)(const __attribute__((address_space(3))) void*)p;
}

__device__ __forceinline__ f32x4 dsr_b128(unsigned addr) {
    f32x4 r;
    asm volatile("ds_read_b128 %0, %1" : "=v"(r) : "v"(addr));
    return r;
}

// Kernel 2 (fast): log2-domain alpha recursion. One block per batch item.
// Wave 0 runs the DP; waves 1-3 double-buffer 64-t chunks of lpg into LDS.
// DP wave's lp reads are inline-asm ds_read_b128 issued 2 groups (8 steps)
// ahead, drained by counted s_waitcnt lgkmcnt(4) + sched_barrier — LDS
// latency is fully off the serial chain.
__global__ __launch_bounds__(256) void k_dp_fast(const float* __restrict__ lpg,
                                                 const int* __restrict__ y,
                                                 const int* __restrict__ xlens,
                                                 const int* __restrict__ ylens,
                                                 float* __restrict__ nll_out) {
    __shared__ alignas(16) float sbuf[2][CHUNKF];
    const int n = blockIdx.x;
    const int wid = threadIdx.x >> 6;
    const int l = threadIdx.x & 63;
    const char* src = (const char*)(lpg + (size_t)n * (kT / 4) * kRow);

    auto stage = [&](int c, int b) {
        const int wbase = (wid - 1) * 64;  // wave-uniform
        const char* gs = src + (size_t)c * CHUNKB;
        char* ls = (char*)&sbuf[b][0];
#pragma unroll
        for (int r = 0; r < (CHUNKB / 16 + 191) / 192; ++r) {
            const int wi = wbase + r * 192;  // wave-uniform word index
            if (wi + l < CHUNKB / 16) {
                __builtin_amdgcn_global_load_lds(
                    (const __attribute__((address_space(1))) void*)(gs + (size_t)(wi + l) * 16),
                    (__attribute__((address_space(3))) void*)(ls + (size_t)wi * 16), 16, 0, 0);
            }
        }
    };

    if (wid > 0) stage(0, 0);
    __syncthreads();

    const int yl = ylens[n];
    const int xl = xlens[n];
    const int ycur = y[(n << 6) + l];
    const int yprev = __shfl_up(ycur, 1);
    const bool skip = (l >= 1) && (ycur != yprev);  // skip into state 2l+1
    const int lgrp = l >> 4;                        // 16-lane row id

    float aA = NEGV, aB = NEGV, aC = NEGV;  // states 2l, 2l+1; lane0: state 128
    if (wid == 0) {
        aA = (l == 0) ? sbuf[0][0] : NEGV;  // lp[t=0][s=0]
        aB = (l == 0) ? sbuf[0][4] : NEGV;  // lp[t=0][s=1]
        // Drain the init reads so asm lgkmcnt counting starts clean.
        asm volatile("s_waitcnt lgkmcnt(0)" ::: "memory");
        __builtin_amdgcn_sched_barrier(0);
    }

    for (int c = 0; c < NCHUNK; ++c) {
        if (wid > 0) {
            if (c + 1 < NCHUNK) stage(c + 1, (c + 1) & 1);
        } else {
            const unsigned base = lds_off(&sbuf[c & 1][0]);
            const unsigned a_pb = base;                          // blank quad (bcast)
            const unsigned a_py = base + 16u + 16u * (unsigned)l;  // label quad
            const int tb0 = c * CHUNK;

            auto chunk_body = [&](auto frzc) {
                constexpr bool FRZV = decltype(frzc)::value;
#define STEP4(BB, BY, TB)                                                     \
    do {                                                                      \
        dp_step<FRZV>(aA, aB, aC, (BB).x, (BY).x, skip, lgrp, l,              \
                      (((TB) + 0) > 0) & (((TB) + 0) < xl));                  \
        dp_step<FRZV>(aA, aB, aC, (BB).y, (BY).y, skip, lgrp, l,              \
                      (((TB) + 1) > 0) & (((TB) + 1) < xl));                  \
        dp_step<FRZV>(aA, aB, aC, (BB).z, (BY).z, skip, lgrp, l,              \
                      (((TB) + 2) > 0) & (((TB) + 2) < xl));                  \
        dp_step<FRZV>(aA, aB, aC, (BB).w, (BY).w, skip, lgrp, l,              \
                      (((TB) + 3) > 0) & (((TB) + 3) < xl));                  \
    } while (0)
                // Prologue: issue groups 0 and 1 (4 ds_read ops outstanding).
                f32x4 b0b = dsr_b128(a_pb);
                f32x4 b0y = dsr_b128(a_py);
                f32x4 b1b = dsr_b128(a_pb + (unsigned)kRowB);
                f32x4 b1y = dsr_b128(a_py + (unsigned)kRowB);
#pragma unroll
                for (int gp = 0; gp < 8; ++gp) {
                    f32x4 i0b, i0y, i1b, i1y;
                    if (gp < 7) {  // issue group 2gp+2, then drain group 2gp
                        i0b = dsr_b128(a_pb + (unsigned)((2 * gp + 2) * kRowB));
                        i0y = dsr_b128(a_py + (unsigned)((2 * gp + 2) * kRowB));
                        asm volatile("s_waitcnt lgkmcnt(4)" ::: "memory");
                    } else {
                        asm volatile("s_waitcnt lgkmcnt(2)" ::: "memory");
                    }
                    __builtin_amdgcn_sched_barrier(0);
                    STEP4(b0b, b0y, tb0 + 8 * gp);
                    if (gp < 7) {  // issue group 2gp+3, then drain group 2gp+1
                        i1b = dsr_b128(a_pb + (unsigned)((2 * gp + 3) * kRowB));
                        i1y = dsr_b128(a_py + (unsigned)((2 * gp + 3) * kRowB));
                        asm volatile("s_waitcnt lgkmcnt(4)" ::: "memory");
                    } else {
                        asm volatile("s_waitcnt lgkmcnt(0)" ::: "memory");
                    }
                    __builtin_amdgcn_sched_barrier(0);
                    STEP4(b1b, b1y, tb0 + 8 * gp + 4);
                    if (gp < 7) { b0b = i0b; b0y = i0y; b1b = i1b; b1y = i1y; }
                }
#undef STEP4
            };
            if (c == 0 || xl < kT) chunk_body(TrueT{});   // needs t>0 / t<xl guards
            else chunk_body(FalseT{});                    // no per-step cndmasks
        }
        __syncthreads();
    }

    if (wid == 0) {
        // alpha[2*yl] and alpha[2*yl-1]; yl in [16,64]
        const float la = (yl < 64) ? __shfl(aA, yl) : __shfl(aC, 0);
        const float lb = __shfl(aB, yl - 1);
        if (l == 0) {
            float nll = -lse2_2(la, lb) * LN2;  // back to nats
            if (!(isfinite(nll) && nll < 1e29f)) nll = 0.0f;  // zero_infinity
            nll_out[n] = nll / (float)yl;
        }
    }
}

// Fallback DP (no gather workspace): log-domain, gathers raw logits. Slow but correct.
template <int PFB>
__global__ __launch_bounds__(64) void k_dp_fb(const float* __restrict__ logits,
                                              const float* __restrict__ lsearr,
                                              const int* __restrict__ y,
                                              const int* __restrict__ xlens,
                                              const int* __restrict__ ylens,
                                              float* __restrict__ nll_out) {
    const int n = blockIdx.x;
    const int l = threadIdx.x;
    const int yl = ylens[n];
    const int xl = xlens[n];
    const int ycur = y[(n << 6) + l];
    const int yprev = __shfl_up(ycur, 1);
    const bool skip = (l >= 1) && (ycur != yprev);

    auto load_lp = [&](int t, float& lpb, float& lpy) {
        const float* p = logits + ((size_t)t * kN + n) * kC;
        const float d = lsearr[t * kN + n];
        lpb = p[0] - d;
        lpy = p[ycur] - d;
    };

    float lpb0, lpy0;
    load_lp(0, lpb0, lpy0);
    float aA = (l == 0) ? lpb0 : NEGV;
    float aB = (l == 0) ? lpy0 : NEGV;
    float aC = NEGV;

    float pb[PFB], py[PFB];
#pragma unroll
    for (int k = 0; k < PFB; ++k) load_lp(1 + k, pb[k], py[k]);

    for (int tb = 1; tb < kT; tb += PFB) {
#pragma unroll
        for (int k = 0; k < PFB; ++k) {
            const int t = tb + k;
            if (t < kT) {
                const float lpb = pb[k], lpy = py[k];
                if (t + PFB < kT) load_lp(t + PFB, pb[k], py[k]);
                float am1 = __shfl_up(aB, 1);
                if (l == 0) am1 = NEGV;
                const float nA = lpb + lse2_e(aA, am1);
                const float nB = lpy + lse3_e(aB, aA, skip ? am1 : NEGV);
                float nC = aC;
                if (l == 63) nC = lpb + lse2_e(aC, aB);
                if (t < xl) { aA = nA; aB = nB; aC = nC; }
            }
        }
    }

    __shared__ float st[130];
    st[2 * l] = aA;
    st[2 * l + 1] = aB;
    if (l == 63) st[128] = aC;
    __syncthreads();
    if (l == 0) {
        const int end = 2 * yl;
        float nll = -lse2_e(st[end], st[end - 1]);
        if (!(isfinite(nll) && nll < 1e29f)) nll = 0.0f;
        nll_out[n] = nll / (float)yl;
    }
}

__global__ __launch_bounds__(128) void k_reduce(const float* __restrict__ nll,
                                                float* __restrict__ out) {
    const int tid = threadIdx.x;
    float v = nll[tid];
#pragma unroll
    for (int o = 32; o > 0; o >>= 1) v += __shfl_xor(v, o);
    __shared__ float partial[2];
    if ((tid & 63) == 0) partial[tid >> 6] = v;
    __syncthreads();
    if (tid == 0) out[0] = (partial[0] + partial[1]) * (1.0f / (float)kN);
}

extern "C" void kernel_launch(void* const* d_in, const int* in_sizes, int n_in,
                              void* d_out, int out_size, void* d_ws, size_t ws_size,
                              hipStream_t stream) {
    const float* logits = (const float*)d_in[0];
    const int* y = (const int*)d_in[1];
    const int* xlens = (const int*)d_in[2];
    const int* ylens = (const int*)d_in[3];
    float* out = (float*)d_out;

    const size_t need_full =
        (size_t)kN * (kT / 4) * kRow * sizeof(float) + kN * sizeof(float);
    const int rows = kT * kN;

    if (ws_size >= need_full) {
        float* lpg = (float*)d_ws;
        float* nll = lpg + (size_t)kN * (kT / 4) * kRow;
        k_lse<true><<<rows / 4, 256, 0, stream>>>(logits, y, lpg, nullptr);
        k_dp_fast<<<kN, 256, 0, stream>>>(lpg, y, xlens, ylens, nll);
        k_reduce<<<1, kN, 0, stream>>>(nll, out);
    } else {
        float* lsearr = (float*)d_ws;
        float* nll = lsearr + (size_t)rows;
        k_lse<false><<<rows / 4, 256, 0, stream>>>(logits, y, nullptr, lsearr);
        k_dp_fb<8><<<kN, 64, 0, stream>>>(logits, lsearr, y, xlens, ylens, nll);
        k_reduce<<<1, kN, 0, stream>>>(nll, out);
    }
}

// Round 11
// 96.204 us; speedup vs baseline: 1.8073x; 1.5881x over previous
//
#include <hip/hip_runtime.h>
#include <math.h>

// CTC loss forward: T=1024, N=128, C=256, S=64, L=2S+1=129, blank=0.
constexpr int kT = 1024;
constexpr int kN = 128;
constexpr int kC = 256;
constexpr float NEGV = -1e30f;
constexpr int kRow = 260;            // floats per t4-group: 65 states x 4 t's
constexpr int kRowB = kRow * 4;      // 1040 bytes
constexpr int kCH = 32;              // t-steps per chunk per direction
constexpr int kNCH = 512 / kCH;      // 16 chunks per direction
constexpr int kChF = 8 * kRow;       // 2080 floats per chunk (8 t4-groups)
constexpr int kChB = kChF * 4;       // 8320 bytes
constexpr float LOG2E = 1.4426950408889634f;
constexpr float LN2 = 0.6931471805599453f;

#if __has_builtin(__builtin_amdgcn_exp2f)
#define EXP2(x) __builtin_amdgcn_exp2f(x)
#else
#define EXP2(x) exp2f(x)
#endif
#if __has_builtin(__builtin_amdgcn_logf)
#define LOG2(x) __builtin_amdgcn_logf(x)
#else
#define LOG2(x) log2f(x)
#endif

struct TrueT { static constexpr bool value = true; };
struct FalseT { static constexpr bool value = false; };

__device__ __forceinline__ float lse2_2(float a, float b) {  // log2(2^a + 2^b)
    const float m = fmaxf(a, b);
    const float d = fminf(a, b) - m;
    return m + LOG2(1.0f + EXP2(d));
}

__device__ __forceinline__ float lse2_e(float a, float b) {  // ln(e^a + e^b)
    const float m = fmaxf(a, b);
    return m + __logf(1.0f + __expf(fminf(a, b) - m));
}

__device__ __forceinline__ float lse3_e(float a, float b, float c) {
    const float m = fmaxf(fmaxf(a, b), c);
    return m + __logf(__expf(a - m) + __expf(b - m) + __expf(c - m));
}

// Kernel 1: per-row logsumexp over C=256. GATHER mode: block = (n, t4) covers
// 4 consecutive t for one n; writes BASE-2 log-probs in blocked-transposed
// layout lpg[n][t4][s][j] (s=0 blank, s=1+k label k; j=t&3), coalesced via LDS.
template <bool GATHER>
__global__ __launch_bounds__(256) void k_lse(const float* __restrict__ logits,
                                             const int* __restrict__ y,
                                             float* __restrict__ lpg,
                                             float* __restrict__ lse_out) {
    __shared__ float srow[4][kC];
    __shared__ float sT[4][65];
    const int w = threadIdx.x >> 6;
    const int lane = threadIdx.x & 63;
    const int n = blockIdx.x & (kN - 1);
    const int t4 = blockIdx.x >> 7;
    const int t = t4 * 4 + w;
    const int row = t * kN + n;

    const float4 v = reinterpret_cast<const float4*>(logits + (size_t)row * kC)[lane];
    float m = fmaxf(fmaxf(v.x, v.y), fmaxf(v.z, v.w));
#pragma unroll
    for (int o = 32; o > 0; o >>= 1) m = fmaxf(m, __shfl_xor(m, o));
    float s = __expf(v.x - m) + __expf(v.y - m) + __expf(v.z - m) + __expf(v.w - m);
#pragma unroll
    for (int o = 32; o > 0; o >>= 1) s += __shfl_xor(s, o);

    if (GATHER) {
        const float log2s = LOG2(s);
        float* sr = srow[w];
        reinterpret_cast<float4*>(sr)[lane] = v;
        const int cls = y[(n << 6) + lane];  // labels in [1, C)
        sT[w][1 + lane] = (sr[cls] - m) * LOG2E - log2s;
        if (lane == 0) sT[w][0] = (v.x - m) * LOG2E - log2s;  // blank
        __syncthreads();
        float* op = lpg + (size_t)n * (kT / 4) * kRow + (size_t)t4 * kRow;
        const int tid = threadIdx.x;
        op[tid] = sT[tid & 3][tid >> 2];            // idx = s*4 + j
        if (tid < 4) op[256 + tid] = sT[tid][64];   // s = 64, j = tid
    } else {
        if (lane == 0) lse_out[row] = m + __logf(s);
    }
}

// One DP step, log2 domain (validated r7). Works for BOTH directions:
// fwd: A,B = alpha[2l], alpha[2l+1]; C = alpha[128] (lane 0); shuffle = B[l-1],
//      wrap lane0 <- B[63].
// bwd (reversed lane map): A,B = beta[128-2l], beta[127-2l]; C = beta[0]
//      (lane 0); identical shuffle/boundary structure (exact mirror).
template <bool FRZ>
__device__ __forceinline__ void dp_step(float& A, float& B, float& C,
                                        float lpb, float lpy, bool skip,
                                        int lgrp, int l, bool commit) {
    const int bi = __float_as_int(B);
    const int b15 = __builtin_amdgcn_readlane(bi, 15);
    const int b31 = __builtin_amdgcn_readlane(bi, 31);
    const int b47 = __builtin_amdgcn_readlane(bi, 47);
    const int b63 = __builtin_amdgcn_readlane(bi, 63);
    const int bndi = (lgrp == 0) ? b63 : (lgrp == 1) ? b15 : (lgrp == 2) ? b31 : b47;
    const float am1 = __int_as_float(__builtin_amdgcn_update_dpp(
        bndi, bi, 0x111 /*row_shr:1*/, 0xF, 0xF, false));
    const float am1s = skip ? am1 : NEGV;
    // nB = lpy + lse3(B, A, am1s): med3 2-exp form
    const float x = fmaxf(B, A), yv = fminf(B, A);
    const float mB = fmaxf(x, am1s);
    const float dB1 = fmaxf(yv, fminf(x, am1s)) - mB;  // med - max
    const float dB2 = fminf(yv, am1s) - mB;            // min - max
    const float nB = (lpy + mB) + LOG2(1.0f + (EXP2(dB1) + EXP2(dB2)));
    // even-state / extra-state share one lse2 (lane 0's slot computes C)
    const float u = (l == 0) ? C : A;
    const float mA = fmaxf(u, am1);
    const float lseA = mA + LOG2(1.0f + EXP2(fminf(u, am1) - mA));
    const float nA = lpb + ((l == 0) ? A : lseA);
    const float nC = lpb + lseA;  // meaningful at lane 0 only
    if (FRZ) {
        A = commit ? nA : A;
        B = commit ? nB : B;
        C = commit ? nC : C;
    } else {
        A = nA; B = nB; C = nC;
    }
}

// Kernel 2: split forward/backward DP. One block per batch item, 8 waves:
// w0 = alpha (t=1..511), w1 = beta (t=1023..512, reversed lane map), w2-4
// stage the fwd lp stream, w5-7 stage the bwd stream. Merge:
// nll = -lse_s(alpha_511[s] + gamma_511[s]).
__global__ __launch_bounds__(512) void k_dp_split(const float* __restrict__ lpg,
                                                  const int* __restrict__ y,
                                                  const int* __restrict__ xlens,
                                                  const int* __restrict__ ylens,
                                                  float* __restrict__ nll_out) {
    __shared__ alignas(16) float sbf[2][kChF];
    __shared__ alignas(16) float sbb[2][kChF];
    __shared__ float st_f[130];
    __shared__ float st_b[130];
    const int n = blockIdx.x;
    const int wid = threadIdx.x >> 6;
    const int l = threadIdx.x & 63;
    const int lgrp = l >> 4;
    const char* src = (const char*)(lpg + (size_t)n * (kT / 4) * kRow);

    auto stage = [&](int c, int b, bool isF) {
        const int widx = isF ? (wid - 2) : (wid - 5);
        const long off = isF ? (long)c * kChB : (long)(256 - 8 * (c + 1)) * kRowB;
        const char* gs = src + off;
        char* ls = (char*)(isF ? &sbf[b][0] : &sbb[b][0]);
#pragma unroll
        for (int r = 0; r < 3; ++r) {
            const int wi = widx * 64 + r * 192;  // wave-uniform word index
            if (wi + l < kChB / 16) {
                __builtin_amdgcn_global_load_lds(
                    (const __attribute__((address_space(1))) void*)(gs + (size_t)(wi + l) * 16),
                    (__attribute__((address_space(3))) void*)(ls + (size_t)wi * 16), 16, 0, 0);
            }
        }
    };

    if (wid >= 2) stage(0, 0, wid < 5);
    __syncthreads();

    const int yl = ylens[n];
    const int xl = xlens[n];

    if (wid == 0) {
        // ---------------- FORWARD: alpha, t = 1..511 ----------------
        const int ycur = y[(n << 6) + l];
        const int yprev = __shfl_up(ycur, 1);
        const bool skip = (l >= 1) && (ycur != yprev);
        float aA = (l == 0) ? sbf[0][0] : NEGV;  // lp[t=0][s=0]
        float aB = (l == 0) ? sbf[0][4] : NEGV;  // lp[t=0][s=1]
        float aC = NEGV;

        for (int c = 0; c < kNCH; ++c) {
            const float* B = sbf[c & 1];
            const int tb0 = c * kCH;
            auto body = [&](auto frzc) {
                constexpr bool FRZV = decltype(frzc)::value;
                float pb[2][4][4], py[2][4][4];
#define LOADF(H, D)                                                          \
    do {                                                                     \
        _Pragma("unroll") for (int q_ = 0; q_ < 4; ++q_) {                   \
            const int rb_ = (4 * (H) + q_) * kRow;                           \
            const float4 t0_ = *(const float4*)&B[rb_];                      \
            const float4 t1_ = *(const float4*)&B[rb_ + 4 + 4 * l];          \
            pb[D][q_][0] = t0_.x; pb[D][q_][1] = t0_.y;                      \
            pb[D][q_][2] = t0_.z; pb[D][q_][3] = t0_.w;                      \
            py[D][q_][0] = t1_.x; py[D][q_][1] = t1_.y;                      \
            py[D][q_][2] = t1_.z; py[D][q_][3] = t1_.w;                      \
        }                                                                    \
    } while (0)
                LOADF(0, 0);
#pragma unroll
                for (int h = 0; h < 2; ++h) {
                    const int cur = h & 1, nxt = cur ^ 1;
                    if (h < 1) LOADF(1, 1);
#pragma unroll
                    for (int q = 0; q < 4; ++q) {
#pragma unroll
                        for (int j = 0; j < 4; ++j) {
                            const int t = tb0 + 16 * h + 4 * q + j;
                            dp_step<FRZV>(aA, aB, aC, pb[cur][q][j], py[cur][q][j],
                                          skip, lgrp, l, (t > 0) & (t < xl));
                        }
                    }
                }
#undef LOADF
            };
            if (c == 0 || xl < 512) body(TrueT{});
            else body(FalseT{});
            __syncthreads();
        }
        st_f[2 * l] = aA;
        st_f[2 * l + 1] = aB;
        if (l == 0) st_f[128] = aC;
        __syncthreads();

        // ---------------- MERGE ----------------
        const float v0 = st_f[l] + st_b[l];
        const float v1 = st_f[64 + l] + st_b[64 + l];
        const float v2 = (l == 0) ? (st_f[128] + st_b[128]) : NEGV;
        float mm = fmaxf(fmaxf(v0, v1), v2);
#pragma unroll
        for (int o = 32; o > 0; o >>= 1) mm = fmaxf(mm, __shfl_xor(mm, o));
        float sm = EXP2(v0 - mm) + EXP2(v1 - mm) + EXP2(v2 - mm);
#pragma unroll
        for (int o = 32; o > 0; o >>= 1) sm += __shfl_xor(sm, o);
        if (l == 0) {
            float nll;
            if (xl <= 512) {  // beta segment empty: read frozen alpha directly
                nll = -lse2_2(st_f[2 * yl], st_f[2 * yl - 1]) * LN2;
            } else {
                nll = -(mm + LOG2(sm)) * LN2;
            }
            if (!(isfinite(nll) && nll < 1e29f)) nll = 0.0f;  // zero_infinity
            nll_out[n] = nll / (float)yl;
        }
    } else if (wid == 1) {
        // ---------------- BACKWARD: beta, t = 1023..512 (reversed lanes) ----
        // lane l owns states (128-2l, 127-2l); state 0 in lane 0's extra slot.
        const int ycb = y[(n << 6) + 63 - l];     // label of state 127-2l
        const int yup = __shfl_up(ycb, 1);        // y[64-l]
        const bool skipb = (l >= 1) && (ycb != yup);
        const int ls = 64 - yl;                   // seed lane (yl=64 -> 0)
        float bA = NEGV, bB = NEGV, b0 = NEGV;

        for (int c = 0; c < kNCH; ++c) {
            const float* B = sbb[c & 1];
            const int ttop = 1023 - kCH * c;      // t of first (descending) slot
            auto body = [&](auto frzc) {
                constexpr bool FRZV = decltype(frzc)::value;
                float pb[2][4][4], py[2][4][4];
#define LOADB(H, D)                                                          \
    do {                                                                     \
        _Pragma("unroll") for (int q_ = 0; q_ < 4; ++q_) {                   \
            const int rb_ = (7 - 4 * (H) - q_) * kRow;                       \
            const float4 t0_ = *(const float4*)&B[rb_];                      \
            const float4 t1_ = *(const float4*)&B[rb_ + 256 - 4 * l];        \
            pb[D][q_][0] = t0_.x; pb[D][q_][1] = t0_.y;                      \
            pb[D][q_][2] = t0_.z; pb[D][q_][3] = t0_.w;                      \
            py[D][q_][0] = t1_.x; py[D][q_][1] = t1_.y;                      \
            py[D][q_][2] = t1_.z; py[D][q_][3] = t1_.w;                      \
        }                                                                    \
    } while (0)
                LOADB(0, 0);
#pragma unroll
                for (int h = 0; h < 2; ++h) {
                    const int cur = h & 1, nxt = cur ^ 1;
                    if (h < 1) LOADB(1, 1);
#pragma unroll
                    for (int q = 0; q < 4; ++q) {
#pragma unroll
                        for (int jr = 0; jr < 4; ++jr) {
                            const int j = 3 - jr;
                            const int t = ttop - (16 * h + 4 * q + jr);
                            const float lpb = pb[cur][q][j];
                            const float lpy = py[cur][q][j];
                            dp_step<FRZV>(bA, bB, b0, lpb, lpy, skipb, lgrp, l,
                                          (t >= 512) & (t <= xl - 2));
                            if (FRZV) {  // seed beta_{xl-1} in-stream
                                const bool ss = (t == xl - 1);
                                bA = ss ? ((l == ls) ? lpb : NEGV) : bA;
                                bB = ss ? ((l == ls) ? lpy : NEGV) : bB;
                                b0 = ss ? NEGV : b0;
                            }
                        }
                    }
                }
#undef LOADB
            };
            if (c == 0 || xl < kT) body(TrueT{});
            else body(FalseT{});
            __syncthreads();
        }
        // gamma_511[s] = lse(beta[s], beta[s+1], allow? beta[s+2]) = one more
        // mirror step with lp = 0 (unconditional).
        dp_step<false>(bA, bB, b0, 0.0f, 0.0f, skipb, lgrp, l, true);
        st_b[128 - 2 * l] = bA;
        st_b[127 - 2 * l] = bB;
        if (l == 0) st_b[0] = b0;
        __syncthreads();
    } else {
        // ---------------- STAGERS ----------------
        for (int c = 0; c < kNCH; ++c) {
            if (c + 1 < kNCH) stage(c + 1, (c + 1) & 1, wid < 5);
            __syncthreads();
        }
        __syncthreads();  // match the post-loop barrier
    }
}

// Fallback DP (no gather workspace): log-domain, gathers raw logits. Slow but correct.
template <int PFB>
__global__ __launch_bounds__(64) void k_dp_fb(const float* __restrict__ logits,
                                              const float* __restrict__ lsearr,
                                              const int* __restrict__ y,
                                              const int* __restrict__ xlens,
                                              const int* __restrict__ ylens,
                                              float* __restrict__ nll_out) {
    const int n = blockIdx.x;
    const int l = threadIdx.x;
    const int yl = ylens[n];
    const int xl = xlens[n];
    const int ycur = y[(n << 6) + l];
    const int yprev = __shfl_up(ycur, 1);
    const bool skip = (l >= 1) && (ycur != yprev);

    auto load_lp = [&](int t, float& lpb, float& lpy) {
        const float* p = logits + ((size_t)t * kN + n) * kC;
        const float d = lsearr[t * kN + n];
        lpb = p[0] - d;
        lpy = p[ycur] - d;
    };

    float lpb0, lpy0;
    load_lp(0, lpb0, lpy0);
    float aA = (l == 0) ? lpb0 : NEGV;
    float aB = (l == 0) ? lpy0 : NEGV;
    float aC = NEGV;

    float pb[PFB], py[PFB];
#pragma unroll
    for (int k = 0; k < PFB; ++k) load_lp(1 + k, pb[k], py[k]);

    for (int tb = 1; tb < kT; tb += PFB) {
#pragma unroll
        for (int k = 0; k < PFB; ++k) {
            const int t = tb + k;
            if (t < kT) {
                const float lpb = pb[k], lpy = py[k];
                if (t + PFB < kT) load_lp(t + PFB, pb[k], py[k]);
                float am1 = __shfl_up(aB, 1);
                if (l == 0) am1 = NEGV;
                const float nA = lpb + lse2_e(aA, am1);
                const float nB = lpy + lse3_e(aB, aA, skip ? am1 : NEGV);
                float nC = aC;
                if (l == 63) nC = lpb + lse2_e(aC, aB);
                if (t < xl) { aA = nA; aB = nB; aC = nC; }
            }
        }
    }

    __shared__ float st[130];
    st[2 * l] = aA;
    st[2 * l + 1] = aB;
    if (l == 63) st[128] = aC;
    __syncthreads();
    if (l == 0) {
        const int end = 2 * yl;
        float nll = -lse2_e(st[end], st[end - 1]);
        if (!(isfinite(nll) && nll < 1e29f)) nll = 0.0f;
        nll_out[n] = nll / (float)yl;
    }
}

__global__ __launch_bounds__(128) void k_reduce(const float* __restrict__ nll,
                                                float* __restrict__ out) {
    const int tid = threadIdx.x;
    float v = nll[tid];
#pragma unroll
    for (int o = 32; o > 0; o >>= 1) v += __shfl_xor(v, o);
    __shared__ float partial[2];
    if ((tid & 63) == 0) partial[tid >> 6] = v;
    __syncthreads();
    if (tid == 0) out[0] = (partial[0] + partial[1]) * (1.0f / (float)kN);
}

extern "C" void kernel_launch(void* const* d_in, const int* in_sizes, int n_in,
                              void* d_out, int out_size, void* d_ws, size_t ws_size,
                              hipStream_t stream) {
    const float* logits = (const float*)d_in[0];
    const int* y = (const int*)d_in[1];
    const int* xlens = (const int*)d_in[2];
    const int* ylens = (const int*)d_in[3];
    float* out = (float*)d_out;

    const size_t need_full =
        (size_t)kN * (kT / 4) * kRow * sizeof(float) + kN * sizeof(float);
    const int rows = kT * kN;

    if (ws_size >= need_full) {
        float* lpg = (float*)d_ws;
        float* nll = lpg + (size_t)kN * (kT / 4) * kRow;
        k_lse<true><<<rows / 4, 256, 0, stream>>>(logits, y, lpg, nullptr);
        k_dp_split<<<kN, 512, 0, stream>>>(lpg, y, xlens, ylens, nll);
        k_reduce<<<1, kN, 0, stream>>>(nll, out);
    } else {
        float* lsearr = (float*)d_ws;
        float* nll = lsearr + (size_t)rows;
        k_lse<false><<<rows / 4, 256, 0, stream>>>(logits, y, nullptr, lsearr);
        k_dp_fb<8><<<kN, 64, 0, stream>>>(logits, lsearr, y, xlens, ylens, nll);
        k_reduce<<<1, kN, 0, stream>>>(nll, out);
    }
}